// Round 7
// baseline (116.670 us; speedup 1.0000x reference)
//
#include <hip/hip_runtime.h>

#define NPTS   16384
#define NPAIRS 65536

// ws layout (bytes):
//   [0,      131072)  float2 xt[16384]        {x0, x1}
//   [131072, 147456)  double partPart[2048]   k_part per-block partials (upper-tri sum)
//   [147456, 149504)  double kldPart[256]     k_prep per-wave point partials
//   [149504, 157696)  double s1Part[1024]     k_prep per-wave pair partials: pij*(log pij + log1p(d^2))
//   [157696, 165888)  double s2Part[1024]     k_prep per-wave pair partials: pij
//   [165888, 165892)  uint   doneCnt          k_part completion counter (zeroed by k_prep)

__device__ inline float waveReduceF(float v) {
#pragma unroll
    for (int o = 32; o > 0; o >>= 1) v += __shfl_down(v, o, 64);
    return v;
}

// ---------------- kernel A: reparam table + per-pair loss + counter init ----------------
__global__ __launch_bounds__(256) void k_prep(
        const float2* __restrict__ mu, const float2* __restrict__ lv,
        const float2* __restrict__ ef,
        const float* __restrict__ pij, const int* __restrict__ ii,
        const int* __restrict__ jj,
        const float2* __restrict__ ei, const float2* __restrict__ ej,
        float2* __restrict__ xt,
        double* __restrict__ kldPart, double* __restrict__ s1Part,
        double* __restrict__ s2Part, unsigned int* __restrict__ doneCnt) {
    int b = blockIdx.x;
    int tid = threadIdx.x;
    int wave = tid >> 6;
    if (b == 0 && tid == 0) *doneCnt = 0u;   // init for k_part's last-block detect
    if (b < NPTS / 256) {
        int i = b * 256 + tid;
        float2 m = mu[i], l = lv[i], e = ef[i];
        float x0 = fmaf(e.x, expf(0.5f * l.x), m.x);
        float x1 = fmaf(e.y, expf(0.5f * l.y), m.y);
        xt[i] = make_float2(x0, x1);
        float k = (1.0f + l.x - m.x * m.x - expf(l.x))
                + (1.0f + l.y - m.y * m.y - expf(l.y));
        k = waveReduceF(k);
        if ((tid & 63) == 0) kldPart[b * 4 + wave] = (double)k;
    } else {
        int pb = b - NPTS / 256;
        int p = pb * 256 + tid;
        float pv = pij[p];
        int a = ii[p], bb = jj[p];
        float2 ma = mu[a], la = lv[a], ea = ei[p];
        float2 mb = mu[bb], lb = lv[bb], eb = ej[p];
        float xa0 = fmaf(ea.x, expf(0.5f * la.x), ma.x);
        float xa1 = fmaf(ea.y, expf(0.5f * la.y), ma.y);
        float xb0 = fmaf(eb.x, expf(0.5f * lb.x), mb.x);
        float xb1 = fmaf(eb.y, expf(0.5f * lb.y), mb.y);
        float d0 = xa0 - xb0, d1 = xa1 - xb1;
        float dsq = fmaf(d0, d0, d1 * d1);
        float t = pv * (logf(pv) + log1pf(dsq));
        float s1 = waveReduceF(t);
        float s2 = waveReduceF(pv);
        if ((tid & 63) == 0) {
            s1Part[pb * 4 + wave] = (double)s1;
            s2Part[pb * 4 + wave] = (double)s2;
        }
    }
}

// ---------------- kernel B: N^2 normalizer (balanced upper triangle) + fused final ----------------
// part = 2 * sum_{j>i} 1/(1+|xi-xj|^2).  Block (bx,by): rows [64*by, 64*by+64),
// columns {j : j == bx (mod 8)} in chunks of 2048; chunk k live iff k >= kb,
// boundary-masked iff k == kb, where kb = by>>5.  Per-CU work is exactly 36
// chunk-panels (kb = 0..7 once per CU) -> balanced triangle.
// Last finishing block (atomic counter) reduces all partials and writes out.
template<int KB>
__device__ __forceinline__ float partBody(const float2* __restrict__ xt,
                                          int bx, int rowBase, int tid) {
    constexpr int NK = 8 - KB;
    float cx[NK], cy[NK], a[NK];
    int j0 = bx + 8 * (tid + 256 * KB);
#pragma unroll
    for (int m = 0; m < NK; ++m) {
        float2 c = xt[j0 + 2048 * m];
        cx[m] = c.x; cy[m] = c.y; a[m] = 0.0f;
    }
    float2 rv = xt[rowBase + (tid & 63)];
#pragma unroll 8
    for (int r = 0; r < 64; ++r) {
        float rx = __int_as_float(__builtin_amdgcn_readlane(__float_as_int(rv.x), r));
        float ry = __int_as_float(__builtin_amdgcn_readlane(__float_as_int(rv.y), r));
        {   // chunk KB: boundary, mask j > i
            float d0 = rx - cx[0], d1 = ry - cy[0];
            float e = fmaf(d1, d1, fmaf(d0, d0, 1.0f));
            float v = __builtin_amdgcn_rcpf(e);
            a[0] += (j0 > rowBase + r) ? v : 0.0f;
        }
#pragma unroll
        for (int m = 1; m < NK; ++m) {   // chunks > KB: fully live
            float d0 = rx - cx[m], d1 = ry - cy[m];
            float e = fmaf(d1, d1, fmaf(d0, d0, 1.0f));
            a[m] += __builtin_amdgcn_rcpf(e);
        }
    }
    float s = 0.0f;
#pragma unroll
    for (int m = 0; m < NK; ++m) s += a[m];
    return s;
}

__global__ __launch_bounds__(256) void k_part(
        const float2* __restrict__ xt, double* __restrict__ partPart,
        const double* __restrict__ kldPart, const double* __restrict__ s1Part,
        const double* __restrict__ s2Part, unsigned int* __restrict__ doneCnt,
        float* __restrict__ out) {
    int bx = blockIdx.x, by = blockIdx.y;
    int rowBase = by * 64;
    int kb = by >> 5;
    int tid = threadIdx.x;
    float s = 0.0f;
    switch (kb) {               // wave-uniform branch
        case 0: s = partBody<0>(xt, bx, rowBase, tid); break;
        case 1: s = partBody<1>(xt, bx, rowBase, tid); break;
        case 2: s = partBody<2>(xt, bx, rowBase, tid); break;
        case 3: s = partBody<3>(xt, bx, rowBase, tid); break;
        case 4: s = partBody<4>(xt, bx, rowBase, tid); break;
        case 5: s = partBody<5>(xt, bx, rowBase, tid); break;
        case 6: s = partBody<6>(xt, bx, rowBase, tid); break;
        default: s = partBody<7>(xt, bx, rowBase, tid); break;
    }
    s = waveReduceF(s);
    __shared__ float ws4[4];
    __shared__ bool isLast;
    if ((tid & 63) == 0) ws4[tid >> 6] = s;
    __syncthreads();
    if (tid == 0) {
        partPart[by * 8 + bx] =
            ((double)ws4[0] + (double)ws4[1]) + ((double)ws4[2] + (double)ws4[3]);
        __threadfence();                         // publish partial
        unsigned int old = atomicAdd(doneCnt, 1u);
        isLast = (old == 2047u);
    }
    __syncthreads();
    if (!isLast) return;

    // ---- fused final reduce (one block, 256 threads) ----
    __threadfence();                             // acquire all partials
    double ps = 0.0;
#pragma unroll
    for (int k = 0; k < 8; ++k) ps += partPart[tid + 256 * k];
    double kld = kldPart[tid];
    double s1 = 0.0, s2 = 0.0;
#pragma unroll
    for (int k = 0; k < 4; ++k) { s1 += s1Part[tid + 256 * k]; s2 += s2Part[tid + 256 * k]; }
#pragma unroll
    for (int o = 32; o > 0; o >>= 1) {
        ps  += __shfl_down(ps, o, 64);
        kld += __shfl_down(kld, o, 64);
        s1  += __shfl_down(s1, o, 64);
        s2  += __shfl_down(s2, o, 64);
    }
    __shared__ double red[4][4];
    if ((tid & 63) == 0) {
        int w = tid >> 6;
        red[0][w] = ps; red[1][w] = kld; red[2][w] = s1; red[3][w] = s2;
    }
    __syncthreads();
    if (tid == 0) {
        double pst  = (red[0][0] + red[0][1]) + (red[0][2] + red[0][3]);
        double kldt = (red[1][0] + red[1][1]) + (red[1][2] + red[1][3]);
        double s1t  = (red[2][0] + red[2][1]) + (red[2][2] + red[2][3]);
        double s2t  = (red[3][0] + red[3][1]) + (red[3][2] + red[3][3]);
        double part = 2.0 * pst;                 // diagonal cancels: sum_all - N = 2*S_upper
        out[0] = (float)(s1t + s2t * log(part) - 0.5e-7 * kldt);
    }
}

extern "C" void kernel_launch(void* const* d_in, const int* in_sizes, int n_in,
                              void* d_out, int out_size, void* d_ws, size_t ws_size,
                              hipStream_t stream) {
    const float*  pij = (const float*)d_in[0];
    const int*    ii  = (const int*)d_in[1];
    const int*    jj  = (const int*)d_in[2];
    const float2* mu  = (const float2*)d_in[3];
    const float2* lv  = (const float2*)d_in[4];
    const float2* ef  = (const float2*)d_in[5];
    const float2* ei  = (const float2*)d_in[6];
    const float2* ej  = (const float2*)d_in[7];
    float* out = (float*)d_out;

    char* ws = (char*)d_ws;
    float2* xt       = (float2*)ws;
    double* partPart = (double*)(ws + 131072);
    double* kldPart  = (double*)(ws + 147456);
    double* s1Part   = (double*)(ws + 149504);
    double* s2Part   = (double*)(ws + 157696);
    unsigned int* doneCnt = (unsigned int*)(ws + 165888);

    k_prep<<<NPTS / 256 + NPAIRS / 256, 256, 0, stream>>>(mu, lv, ef, pij, ii, jj,
                                                          ei, ej, xt, kldPart, s1Part,
                                                          s2Part, doneCnt);
    dim3 gb(8, 256);
    k_part<<<gb, 256, 0, stream>>>(xt, partPart, kldPart, s1Part, s2Part, doneCnt, out);
}

// Round 14
// 112.021 us; speedup vs baseline: 1.0415x; 1.0415x over previous
//
#include <hip/hip_runtime.h>

#define NPTS   16384
#define NPAIRS 65536

// ws layout (bytes):
//   [0,      131072)  float2 xt[16384]        {x0, x1}
//   [131072, 139264)  double partPart[1024]   k_part per-block partials (upper-tri sum)
//   [147456, 149504)  double kldPart[256]     k_prep per-wave point partials
//   [149504, 157696)  double s1Part[1024]     k_prep per-wave pair partials: pij*(log pij + log1p(d^2))
//   [157696, 165888)  double s2Part[1024]     k_prep per-wave pair partials: pij
//   [165888, 165892)  uint   doneCnt          k_part completion counter (zeroed by k_prep)

__device__ inline float waveReduceF(float v) {
#pragma unroll
    for (int o = 32; o > 0; o >>= 1) v += __shfl_down(v, o, 64);
    return v;
}

// ---------------- kernel A: reparam table + per-pair loss + counter init ----------------
__global__ __launch_bounds__(256) void k_prep(
        const float2* __restrict__ mu, const float2* __restrict__ lv,
        const float2* __restrict__ ef,
        const float* __restrict__ pij, const int* __restrict__ ii,
        const int* __restrict__ jj,
        const float2* __restrict__ ei, const float2* __restrict__ ej,
        float2* __restrict__ xt,
        double* __restrict__ kldPart, double* __restrict__ s1Part,
        double* __restrict__ s2Part, unsigned int* __restrict__ doneCnt) {
    int b = blockIdx.x;
    int tid = threadIdx.x;
    int wave = tid >> 6;
    if (b == 0 && tid == 0) *doneCnt = 0u;   // init for k_part's last-block detect
    if (b < NPTS / 256) {
        int i = b * 256 + tid;
        float2 m = mu[i], l = lv[i], e = ef[i];
        float x0 = fmaf(e.x, expf(0.5f * l.x), m.x);
        float x1 = fmaf(e.y, expf(0.5f * l.y), m.y);
        xt[i] = make_float2(x0, x1);
        float k = (1.0f + l.x - m.x * m.x - expf(l.x))
                + (1.0f + l.y - m.y * m.y - expf(l.y));
        k = waveReduceF(k);
        if ((tid & 63) == 0) kldPart[b * 4 + wave] = (double)k;
    } else {
        int pb = b - NPTS / 256;
        int p = pb * 256 + tid;
        float pv = pij[p];
        int a = ii[p], bb = jj[p];
        float2 ma = mu[a], la = lv[a], ea = ei[p];
        float2 mb = mu[bb], lb = lv[bb], eb = ej[p];
        float xa0 = fmaf(ea.x, expf(0.5f * la.x), ma.x);
        float xa1 = fmaf(ea.y, expf(0.5f * la.y), ma.y);
        float xb0 = fmaf(eb.x, expf(0.5f * lb.x), mb.x);
        float xb1 = fmaf(eb.y, expf(0.5f * lb.y), mb.y);
        float d0 = xa0 - xb0, d1 = xa1 - xb1;
        float dsq = fmaf(d0, d0, d1 * d1);
        float t = pv * (logf(pv) + log1pf(dsq));
        float s1 = waveReduceF(t);
        float s2 = waveReduceF(pv);
        if ((tid & 63) == 0) {
            s1Part[pb * 4 + wave] = (double)s1;
            s2Part[pb * 4 + wave] = (double)s2;
        }
    }
}

// ---------------- kernel B: N^2 normalizer (balanced triangle, paired panels) ----------------
// part = 2 * sum_{j>i} 1/(1+|xi-xj|^2).  Columns {j == bx (mod 8)} in 8 chunks
// of 256 (thread tid owns column bx + 8*(tid + 256*k) of chunk k).  Row-panel
// by (64 rows): chunk k dead if k < kb, boundary-masked if k == kb, live if
// k > kb, kb = by>>5.  Work(by) = 8-kb.  Block (bx, by<128) processes BOTH
// row-panel by (kb in 0..3) and its complement 255-by (kb' = 7-kb):
// 9 chunk-panels for every block -> zero tail skew, flat occupancy.
// Last finishing block (atomic counter) reduces all partials and writes out.
template<int KB>
__device__ __forceinline__ float partBody(const float2* __restrict__ xt,
                                          int bx, int rowBase, int tid) {
    constexpr int NK = 8 - KB;
    float cx[NK], cy[NK], a[NK];
    int j0 = bx + 8 * (tid + 256 * KB);
#pragma unroll
    for (int m = 0; m < NK; ++m) {
        float2 c = xt[j0 + 2048 * m];
        cx[m] = c.x; cy[m] = c.y; a[m] = 0.0f;
    }
    float2 rv = xt[rowBase + (tid & 63)];
#pragma unroll 8
    for (int r = 0; r < 64; ++r) {
        float rx = __int_as_float(__builtin_amdgcn_readlane(__float_as_int(rv.x), r));
        float ry = __int_as_float(__builtin_amdgcn_readlane(__float_as_int(rv.y), r));
        {   // chunk KB: boundary, mask j > i
            float d0 = rx - cx[0], d1 = ry - cy[0];
            float e = fmaf(d1, d1, fmaf(d0, d0, 1.0f));
            float v = __builtin_amdgcn_rcpf(e);
            a[0] += (j0 > rowBase + r) ? v : 0.0f;
        }
#pragma unroll
        for (int m = 1; m < NK; ++m) {   // chunks > KB: fully live
            float d0 = rx - cx[m], d1 = ry - cy[m];
            float e = fmaf(d1, d1, fmaf(d0, d0, 1.0f));
            a[m] += __builtin_amdgcn_rcpf(e);
        }
    }
    float s = 0.0f;
#pragma unroll
    for (int m = 0; m < NK; ++m) s += a[m];
    return s;
}

__global__ __launch_bounds__(256) void k_part(
        const float2* __restrict__ xt, double* __restrict__ partPart,
        const double* __restrict__ kldPart, const double* __restrict__ s1Part,
        const double* __restrict__ s2Part, unsigned int* __restrict__ doneCnt,
        float* __restrict__ out) {
    int bx = blockIdx.x, by = blockIdx.y;        // by in [0,128)
    int rb1 = by * 64;                           // kb  = by>>5 in 0..3
    int rb2 = (255 - by) * 64;                   // kb' = 7 - (by>>5)
    int tid = threadIdx.x;
    float s = 0.0f;
    switch (by >> 5) {               // wave-uniform branch, static templates
        case 0:  s = partBody<0>(xt, bx, rb1, tid) + partBody<7>(xt, bx, rb2, tid); break;
        case 1:  s = partBody<1>(xt, bx, rb1, tid) + partBody<6>(xt, bx, rb2, tid); break;
        case 2:  s = partBody<2>(xt, bx, rb1, tid) + partBody<5>(xt, bx, rb2, tid); break;
        default: s = partBody<3>(xt, bx, rb1, tid) + partBody<4>(xt, bx, rb2, tid); break;
    }
    s = waveReduceF(s);
    __shared__ float ws4[4];
    __shared__ bool isLast;
    if ((tid & 63) == 0) ws4[tid >> 6] = s;
    __syncthreads();
    if (tid == 0) {
        partPart[by * 8 + bx] =
            ((double)ws4[0] + (double)ws4[1]) + ((double)ws4[2] + (double)ws4[3]);
        __threadfence();                         // publish partial
        unsigned int old = atomicAdd(doneCnt, 1u);
        isLast = (old == 1023u);
    }
    __syncthreads();
    if (!isLast) return;

    // ---- fused final reduce (one block, 256 threads) ----
    __threadfence();                             // acquire all partials
    double ps = 0.0;
#pragma unroll
    for (int k = 0; k < 4; ++k) ps += partPart[tid + 256 * k];
    double kld = kldPart[tid];
    double s1 = 0.0, s2 = 0.0;
#pragma unroll
    for (int k = 0; k < 4; ++k) { s1 += s1Part[tid + 256 * k]; s2 += s2Part[tid + 256 * k]; }
#pragma unroll
    for (int o = 32; o > 0; o >>= 1) {
        ps  += __shfl_down(ps, o, 64);
        kld += __shfl_down(kld, o, 64);
        s1  += __shfl_down(s1, o, 64);
        s2  += __shfl_down(s2, o, 64);
    }
    __shared__ double red[4][4];
    if ((tid & 63) == 0) {
        int w = tid >> 6;
        red[0][w] = ps; red[1][w] = kld; red[2][w] = s1; red[3][w] = s2;
    }
    __syncthreads();
    if (tid == 0) {
        double pst  = (red[0][0] + red[0][1]) + (red[0][2] + red[0][3]);
        double kldt = (red[1][0] + red[1][1]) + (red[1][2] + red[1][3]);
        double s1t  = (red[2][0] + red[2][1]) + (red[2][2] + red[2][3]);
        double s2t  = (red[3][0] + red[3][1]) + (red[3][2] + red[3][3]);
        double part = 2.0 * pst;                 // diagonal cancels: sum_all - N = 2*S_upper
        out[0] = (float)(s1t + s2t * log(part) - 0.5e-7 * kldt);
    }
}

extern "C" void kernel_launch(void* const* d_in, const int* in_sizes, int n_in,
                              void* d_out, int out_size, void* d_ws, size_t ws_size,
                              hipStream_t stream) {
    const float*  pij = (const float*)d_in[0];
    const int*    ii  = (const int*)d_in[1];
    const int*    jj  = (const int*)d_in[2];
    const float2* mu  = (const float2*)d_in[3];
    const float2* lv  = (const float2*)d_in[4];
    const float2* ef  = (const float2*)d_in[5];
    const float2* ei  = (const float2*)d_in[6];
    const float2* ej  = (const float2*)d_in[7];
    float* out = (float*)d_out;

    char* ws = (char*)d_ws;
    float2* xt       = (float2*)ws;
    double* partPart = (double*)(ws + 131072);
    double* kldPart  = (double*)(ws + 147456);
    double* s1Part   = (double*)(ws + 149504);
    double* s2Part   = (double*)(ws + 157696);
    unsigned int* doneCnt = (unsigned int*)(ws + 165888);

    k_prep<<<NPTS / 256 + NPAIRS / 256, 256, 0, stream>>>(mu, lv, ef, pij, ii, jj,
                                                          ei, ej, xt, kldPart, s1Part,
                                                          s2Part, doneCnt);
    dim3 gb(8, 128);
    k_part<<<gb, 256, 0, stream>>>(xt, partPart, kldPart, s1Part, s2Part, doneCnt, out);
}